// Round 18
// baseline (297.623 us; speedup 1.0000x reference)
//
#include <hip/hip_runtime.h>

#define PP 2048     // P (pred rows)
#define SSEQ 2048   // S (key rows)
#define DDIM 1024   // D
#define NH 16       // heads
#define DH 64       // head dim

typedef __attribute__((ext_vector_type(4))) float f32x4;
typedef __attribute__((ext_vector_type(8))) short bf16x8;
typedef __attribute__((ext_vector_type(4))) short bf16x4;

__device__ __forceinline__ short f2bf(float f) {
  unsigned u = __builtin_bit_cast(unsigned, f);
  u += 0x7FFFu + ((u >> 16) & 1u);   // RNE
  return (short)(u >> 16);
}
__device__ __forceinline__ float bf2f(unsigned short u) {
  return __builtin_bit_cast(float, ((unsigned)u) << 16);
}
__device__ __forceinline__ void gld_lds16(const void* g, void* l) {
  __builtin_amdgcn_global_load_lds(
      (const __attribute__((address_space(1))) void*)g,
      (__attribute__((address_space(3))) void*)l, 16, 0, 0);
}

// ---------------- bf16 conversion: 4 weight matrices only ----------------
__global__ __launch_bounds__(256) void cvt4(
    const float* __restrict__ s0, const float* __restrict__ s1,
    const float* __restrict__ s2, const float* __restrict__ s3,
    unsigned short* __restrict__ d0, unsigned short* __restrict__ d1,
    unsigned short* __restrict__ d2, unsigned short* __restrict__ d3) {
  const int z = blockIdx.y;
  const float* s = (z == 0) ? s0 : (z == 1) ? s1 : (z == 2) ? s2 : s3;
  unsigned short* d = (z == 0) ? d0 : (z == 1) ? d1 : (z == 2) ? d2 : d3;
  const size_t i = ((size_t)blockIdx.x * 256 + threadIdx.x) * 8;
  const float4 x0 = *(const float4*)(s + i);
  const float4 x1 = *(const float4*)(s + i + 4);
  bf16x8 o;
  o[0] = f2bf(x0.x); o[1] = f2bf(x0.y); o[2] = f2bf(x0.z); o[3] = f2bf(x0.w);
  o[4] = f2bf(x1.x); o[5] = f2bf(x1.y); o[6] = f2bf(x1.z); o[7] = f2bf(x1.w);
  *(bf16x8*)(d + i) = o;
}

// ---------------- GEMM: Y[2048][1024] = A @ B^T + bias ------
// 128x128 tile, BK=32, 4 waves (2x2). XF32: A fp32, VALU-staged cvt;
// else A bf16 via gld_lds. B always bf16 via gld_lds.
template<int XF32, int YF32>
__device__ __forceinline__ void gemm128_body(
    const void* __restrict__ Av, const unsigned short* __restrict__ B,
    const float* __restrict__ bias, void* __restrict__ Yv) {
  __shared__ unsigned short As[4096];   // 128x32 linear
  __shared__ unsigned short Bs[4096];
  const int tid = threadIdx.x, lane = tid & 63, w = tid >> 6;
  const int m0 = blockIdx.y * 128, n0 = blockIdx.x * 128;
  const int g = lane >> 4, ln = lane & 15;
  const int wm = (w >> 1) * 64, wn = (w & 1) * 64;
  const int sr = tid >> 2, sc = (tid & 3) * 8;
  unsigned short* asd0 = As + w * 512;
  unsigned short* asd1 = As + 2048 + w * 512;
  unsigned short* bsd0 = Bs + w * 512;
  unsigned short* bsd1 = Bs + 2048 + w * 512;
  f32x4 acc[4][4] = {};
  for (int k0 = 0; k0 < DDIM; k0 += 32) {
    __syncthreads();
    if (XF32) {
      const float* A = (const float*)Av;
#pragma unroll
      for (int pass = 0; pass < 4; ++pass) {
        const int e = pass * 1024 + tid * 4;
        const int r = e >> 5, c = e & 31;
        const float4 x = *(const float4*)(A + (size_t)(m0 + r) * DDIM + k0 + c);
        bf16x4 xb; xb[0] = f2bf(x.x); xb[1] = f2bf(x.y); xb[2] = f2bf(x.z); xb[3] = f2bf(x.w);
        *(bf16x4*)&As[r * 32 + c] = xb;
      }
    } else {
      const unsigned short* A = (const unsigned short*)Av;
      gld_lds16(A + (size_t)(m0 + sr) * DDIM + k0 + sc, asd0);
      gld_lds16(A + (size_t)(m0 + 64 + sr) * DDIM + k0 + sc, asd1);
    }
    gld_lds16(B + (size_t)(n0 + sr) * DDIM + k0 + sc, bsd0);
    gld_lds16(B + (size_t)(n0 + 64 + sr) * DDIM + k0 + sc, bsd1);
    __syncthreads();
    bf16x8 a[4], b[4];
#pragma unroll
    for (int mi = 0; mi < 4; ++mi) a[mi] = *(const bf16x8*)&As[(wm + mi * 16 + ln) * 32 + g * 8];
#pragma unroll
    for (int ni = 0; ni < 4; ++ni) b[ni] = *(const bf16x8*)&Bs[(wn + ni * 16 + ln) * 32 + g * 8];
#pragma unroll
    for (int mi = 0; mi < 4; ++mi)
#pragma unroll
      for (int ni = 0; ni < 4; ++ni)
        acc[mi][ni] = __builtin_amdgcn_mfma_f32_16x16x32_bf16(a[mi], b[ni], acc[mi][ni], 0, 0, 0);
  }
#pragma unroll
  for (int mi = 0; mi < 4; ++mi)
#pragma unroll
    for (int ni = 0; ni < 4; ++ni) {
      const int n = n0 + wn + ni * 16 + ln;
      const float bs = bias[n];
#pragma unroll
      for (int r = 0; r < 4; ++r) {
        const int m = m0 + wm + mi * 16 + g * 4 + r;
        const float v = acc[mi][ni][r] + bs;
        if (YF32) ((float*)Yv)[(size_t)m * DDIM + n] = v;
        else ((unsigned short*)Yv)[(size_t)m * DDIM + n] = (unsigned short)f2bf(v);
      }
    }
}

__global__ __launch_bounds__(256, 2) void qkv_gemm(
    const float* __restrict__ Q, const float* __restrict__ K, const float* __restrict__ V,
    const unsigned short* __restrict__ Wq, const unsigned short* __restrict__ Wk,
    const unsigned short* __restrict__ Wv,
    const float* __restrict__ bq, const float* __restrict__ bk, const float* __restrict__ bv,
    unsigned short* __restrict__ qo, unsigned short* __restrict__ ko,
    unsigned short* __restrict__ vo) {
  const int z = blockIdx.z;
  gemm128_body<1, 0>((z == 0) ? (const void*)Q : (z == 1) ? (const void*)K : (const void*)V,
                     (z == 0) ? Wq : (z == 1) ? Wk : Wv,
                     (z == 0) ? bq : (z == 1) ? bk : bv,
                     (z == 0) ? qo : (z == 1) ? ko : vo);
}

__global__ __launch_bounds__(256, 2) void out_gemm(
    const unsigned short* __restrict__ A, const unsigned short* __restrict__ B,
    const float* __restrict__ bias, float* __restrict__ Y) {
  gemm128_body<0, 1>(A, B, bias, Y);
}

// ---------------- V transpose: vT[d][s] = vb[s][d] ----------------
__global__ __launch_bounds__(256) void transpose_v(
    const unsigned short* __restrict__ vb, unsigned short* __restrict__ vT) {
  __shared__ unsigned short t[64][72];
  const int tid = threadIdx.x;
  const int sb = blockIdx.x * 64, db = blockIdx.y * 64;
#pragma unroll
  for (int pass = 0; pass < 2; ++pass) {
    const int e = pass * 2048 + tid * 8;
    const int r = e >> 6, c = e & 63;
    *(bf16x8*)&t[r][c] = *(const bf16x8*)(vb + (size_t)(sb + r) * DDIM + db + c);
  }
  __syncthreads();
#pragma unroll
  for (int pass = 0; pass < 2; ++pass) {
    const int e = pass * 2048 + tid * 8;
    const int r = e >> 6, c = e & 63;   // r: d row, c: s col
    bf16x8 ov;
#pragma unroll
    for (int u = 0; u < 8; ++u) ov[u] = (short)t[c + u][r];
    *(bf16x8*)(vT + (size_t)(db + r) * SSEQ + sb + c) = ov;
  }
}

// ---------------- scorespv v5 (R16 champion, byte-identical) ----------------
__global__ __launch_bounds__(256, 2) void scorespv(
    const unsigned short* __restrict__ qb, const unsigned short* __restrict__ kb,
    const unsigned short* __restrict__ vT,
    const float* __restrict__ prev, const float* __restrict__ ch_gate,
    float* __restrict__ raw, float* __restrict__ l_row,
    unsigned short* __restrict__ ctx) {
  __shared__ float Rs[4][16][132];          // 33.8KB
  __shared__ float lS[4][16];
  __shared__ unsigned short Ks[2][8192];    // 2 x (128 rows x 64 cols) = 32KB
  const int tid = threadIdx.x, lane = tid & 63, w = tid >> 6;
  const int b = blockIdx.x;
  const int h = (b & 7) * 2 + ((b >> 3) & 1);   // XCD-local head pairs
  const int pt = b >> 4;                         // 0..31
  const int p0 = pt * 64, wr = w * 16;
  const int g = lane >> 4, ln = lane & 15;
  const int myp = p0 + wr + ln;
  const int pc = p0 >> 8;

  const int strow = w * 32 + (lane >> 3);
  const int scol = (((lane & 7) << 4) ^ ((lane >> 3) << 4)) >> 1;

  bf16x8 aq[2];
#pragma unroll
  for (int ks = 0; ks < 2; ++ks)
    aq[ks] = *(const bf16x8*)(qb + (size_t)myp * DDIM + h * DH + ks * 32 + g * 8);

  f32x4 U[4] = {};
  float lsum = 0.f;
  const size_t rowb = ((size_t)myp * NH + h) * SSEQ;

  // prologue: stage K tile 0 + prefetch prev tile 0
#pragma unroll
  for (int i = 0; i < 4; ++i)
    gld_lds16(kb + (size_t)(strow + i * 8) * DDIM + h * DH + scol,
              &Ks[0][(w * 32 + i * 8) * 64]);
  f32x4 pv[8];
#pragma unroll
  for (int ks = 0; ks < 4; ++ks) {
    pv[2 * ks]     = __builtin_nontemporal_load((const f32x4*)(prev + rowb + ks * 32 + g * 8));
    pv[2 * ks + 1] = __builtin_nontemporal_load((const f32x4*)(prev + rowb + ks * 32 + g * 8 + 4));
  }
  __syncthreads();   // K tile 0 staged

  for (int t = 0; t < 16; ++t) {
    const int s0 = t * 128;
    const float gate = (ch_gate[pc * 8 + (s0 >> 8)] >= 0.f) ? 1.f : 0.f;
    if (t < 15) {
#pragma unroll
      for (int i = 0; i < 4; ++i)
        gld_lds16(kb + (size_t)(s0 + 128 + strow + i * 8) * DDIM + h * DH + scol,
                  &Ks[(t + 1) & 1][(w * 32 + i * 8) * 64]);
    }
    const char* Kbuf = (const char*)Ks[t & 1];
#pragma unroll
    for (int half = 0; half < 2; ++half) {
      f32x4 acc[4] = {};
#pragma unroll
      for (int ks = 0; ks < 2; ++ks)
#pragma unroll
        for (int nj = 0; nj < 4; ++nj) {
          const int row = half * 64 + nj * 16 + ln;
          const bf16x8 bk = *(const bf16x8*)(Kbuf + row * 128 + ((ks * 64 + g * 16) ^ ((ln & 7) << 4)));
          acc[nj] = __builtin_amdgcn_mfma_f32_16x16x32_bf16(aq[ks], bk, acc[nj], 0, 0, 0);
        }
#pragma unroll
      for (int nj = 0; nj < 4; ++nj)
#pragma unroll
        for (int r = 0; r < 4; ++r)
          Rs[w][g * 4 + r][half * 64 + nj * 16 + ln] = acc[nj][r];
    }
    f32x4 pvn[8];
    if (t < 15) {
#pragma unroll
      for (int ks = 0; ks < 4; ++ks) {
        pvn[2 * ks]     = __builtin_nontemporal_load((const f32x4*)(prev + rowb + s0 + 128 + ks * 32 + g * 8));
        pvn[2 * ks + 1] = __builtin_nontemporal_load((const f32x4*)(prev + rowb + s0 + 128 + ks * 32 + g * 8 + 4));
      }
    }
    f32x4 v[8];
#pragma unroll
    for (int ks = 0; ks < 4; ++ks)
#pragma unroll
      for (int hf = 0; hf < 2; ++hf) {
        const int c0 = ks * 32 + g * 8 + hf * 4;
        const f32x4 sc = *(const f32x4*)&Rs[w][ln][c0];
        f32x4 vv;
        vv[0] = fmaf(sc[0], 0.125f, pv[ks * 2 + hf][0]) * gate;
        vv[1] = fmaf(sc[1], 0.125f, pv[ks * 2 + hf][1]) * gate;
        vv[2] = fmaf(sc[2], 0.125f, pv[ks * 2 + hf][2]) * gate;
        vv[3] = fmaf(sc[3], 0.125f, pv[ks * 2 + hf][3]) * gate;
        v[ks * 2 + hf] = vv;
        *(f32x4*)(raw + rowb + s0 + c0) = vv;   // normal store -> L3 for attn_norm
      }
    if (s0 <= p0 + wr + 15) {
      bf16x8 pa[4];
#pragma unroll
      for (int ks = 0; ks < 4; ++ks) {
        const int cb = s0 + ks * 32 + g * 8;
        float e[8];
#pragma unroll
        for (int j = 0; j < 4; ++j) {
          e[j]     = (cb + j     <= myp) ? __expf(v[2 * ks][j])     : 0.f;
          e[j + 4] = (cb + j + 4 <= myp) ? __expf(v[2 * ks + 1][j]) : 0.f;
        }
        lsum += ((e[0] + e[1]) + (e[2] + e[3])) + ((e[4] + e[5]) + (e[6] + e[7]));
        bf16x8 pk;
#pragma unroll
        for (int j = 0; j < 8; ++j) pk[j] = f2bf(e[j]);
        pa[ks] = pk;
      }
#pragma unroll
      for (int nj = 0; nj < 4; ++nj) {
        const size_t vb0 = (size_t)(h * DH + nj * 16 + ln) * SSEQ + s0;
        const bf16x8 b0 = *(const bf16x8*)(vT + vb0 + g * 8);
        const bf16x8 b1 = *(const bf16x8*)(vT + vb0 + 32 + g * 8);
        const bf16x8 b2 = *(const bf16x8*)(vT + vb0 + 64 + g * 8);
        const bf16x8 b3 = *(const bf16x8*)(vT + vb0 + 96 + g * 8);
        U[nj] = __builtin_amdgcn_mfma_f32_16x16x32_bf16(pa[0], b0, U[nj], 0, 0, 0);
        U[nj] = __builtin_amdgcn_mfma_f32_16x16x32_bf16(pa[1], b1, U[nj], 0, 0, 0);
        U[nj] = __builtin_amdgcn_mfma_f32_16x16x32_bf16(pa[2], b2, U[nj], 0, 0, 0);
        U[nj] = __builtin_amdgcn_mfma_f32_16x16x32_bf16(pa[3], b3, U[nj], 0, 0, 0);
      }
    }
    if (t < 15) {
#pragma unroll
      for (int i = 0; i < 8; ++i) pv[i] = pvn[i];
    }
    __syncthreads();   // next K tile staged; all waves done with Ks[t&1]
  }
  lsum += __shfl_xor(lsum, 16);
  lsum += __shfl_xor(lsum, 32);
  if (g == 0) {
    lS[w][ln] = lsum;
    l_row[h * PP + myp] = lsum;
  }
  float il4[4];
#pragma unroll
  for (int r = 0; r < 4; ++r) il4[r] = 1.f / lS[w][g * 4 + r];
#pragma unroll
  for (int nj = 0; nj < 4; ++nj)
#pragma unroll
    for (int r = 0; r < 4; ++r) {
      const int p = p0 + wr + g * 4 + r;
      ctx[(size_t)p * DDIM + h * DH + nj * 16 + ln] = (unsigned short)f2bf(U[nj][r] * il4[r]);
    }
}

// ---------------- attn_norm: attn = exp(raw)/l (causal), zeros elsewhere ----
__global__ __launch_bounds__(256) void attn_norm(
    const float* __restrict__ raw, const float* __restrict__ l_row,
    float* __restrict__ attn) {
  const int b = blockIdx.x;
  const int lo = b & 255, k8 = b >> 8;
  const int h = lo & 15, ptb = lo >> 4;
  const int pt = ptb + 16 * k8;                 // 0..127
  const int p0 = pt * 16;
  __shared__ float ilS[16];
  if (threadIdx.x < 16) ilS[threadIdx.x] = 1.f / l_row[h * PP + p0 + threadIdx.x];
  __syncthreads();
  const int limit = ((p0 + 16 + 127) >> 7) << 7;
  const int col = threadIdx.x * 4;
  for (int c0 = 0; c0 < SSEQ; c0 += 1024) {
    const int c = c0 + col;
#pragma unroll 4
    for (int r = 0; r < 16; ++r) {
      const int p = p0 + r;
      const size_t base = ((size_t)p * NH + h) * SSEQ + c;
      f32x4 av = {0.f, 0.f, 0.f, 0.f};
      if (c < limit) {
        const float il = ilS[r];
        const f32x4 rv = *(const f32x4*)(raw + base);
        av[0] = (c + 0 <= p) ? __expf(rv[0]) * il : 0.f;
        av[1] = (c + 1 <= p) ? __expf(rv[1]) * il : 0.f;
        av[2] = (c + 2 <= p) ? __expf(rv[2]) * il : 0.f;
        av[3] = (c + 3 <= p) ? __expf(rv[3]) * il : 0.f;
      }
      __builtin_nontemporal_store(av, (f32x4*)(attn + base));
    }
  }
}

extern "C" void kernel_launch(void* const* d_in, const int* in_sizes, int n_in,
                              void* d_out, int out_size, void* d_ws, size_t ws_size,
                              hipStream_t stream) {
  (void)in_sizes; (void)n_in; (void)out_size; (void)ws_size;
  const float* Q    = (const float*)d_in[0];
  const float* K    = (const float*)d_in[1];
  const float* V    = (const float*)d_in[2];
  const float* prev = (const float*)d_in[3];
  const float* Wq   = (const float*)d_in[4];
  const float* bq   = (const float*)d_in[5];
  const float* Wk   = (const float*)d_in[6];
  const float* bk   = (const float*)d_in[7];
  const float* Wv   = (const float*)d_in[8];
  const float* bv   = (const float*)d_in[9];
  const float* Wo   = (const float*)d_in[10];
  const float* bo   = (const float*)d_in[11];
  const float* ch_gate = (const float*)d_in[12];

  float* out  = (float*)d_out;                       // (2048,1024)
  float* attn = out + (size_t)PP * DDIM;             // (2048,16,2048)
  float* raw  = attn + (size_t)PP * NH * SSEQ;       // (2048,16,2048)

  // ws layout (lifetime-overlapped):
  unsigned short* ws16 = (unsigned short*)d_ws;
  unsigned short* qb   = ws16;                       // 2M elems each
  unsigned short* kb   = qb + 2097152;
  unsigned short* vb   = kb + 2097152;
  unsigned short* vT   = vb + 2097152;
  unsigned short* ctx  = vT + 2097152;               // 2M elems
  float* l_row = (float*)(ctx + 2097152);            // (16,2048) f32
  unsigned short* wqb = (unsigned short*)(l_row + 32768);   // 1M elems each
  unsigned short* wkb = wqb + 1048576;
  unsigned short* wvb = wkb + 1048576;
  unsigned short* wob = wvb + 1048576;

  dim3 blk(256);
  cvt4<<<dim3(512, 4), blk, 0, stream>>>(
      Wq, Wk, Wv, Wo, wqb, wkb, wvb, wob);
  qkv_gemm<<<dim3(DDIM / 128, PP / 128, 3), blk, 0, stream>>>(
      Q, K, V, wqb, wkb, wvb, bq, bk, bv, qb, kb, vb);
  transpose_v<<<dim3(SSEQ / 64, DDIM / 64), blk, 0, stream>>>(vb, vT);
  scorespv<<<dim3(512), blk, 0, stream>>>(
      qb, kb, vT, prev, ch_gate, raw, l_row, ctx);
  attn_norm<<<dim3(2048), blk, 0, stream>>>(raw, l_row, attn);
  out_gemm<<<dim3(DDIM / 128, PP / 128), blk, 0, stream>>>(ctx, wob, bo, out);
}

// Round 19
// 286.872 us; speedup vs baseline: 1.0375x; 1.0375x over previous
//
#include <hip/hip_runtime.h>

#define PP 2048     // P (pred rows)
#define SSEQ 2048   // S (key rows)
#define DDIM 1024   // D
#define NH 16       // heads
#define DH 64       // head dim

typedef __attribute__((ext_vector_type(4))) float f32x4;
typedef __attribute__((ext_vector_type(8))) short bf16x8;
typedef __attribute__((ext_vector_type(4))) short bf16x4;

__device__ __forceinline__ short f2bf(float f) {
  unsigned u = __builtin_bit_cast(unsigned, f);
  u += 0x7FFFu + ((u >> 16) & 1u);   // RNE
  return (short)(u >> 16);
}
__device__ __forceinline__ float bf2f(unsigned short u) {
  return __builtin_bit_cast(float, ((unsigned)u) << 16);
}
__device__ __forceinline__ void gld_lds16(const void* g, void* l) {
  __builtin_amdgcn_global_load_lds(
      (const __attribute__((address_space(1))) void*)g,
      (__attribute__((address_space(3))) void*)l, 16, 0, 0);
}

// ---------------- bf16 conversion: 7 buffers in one launch ----------------
__global__ __launch_bounds__(256) void cvt7(
    const float* __restrict__ s0, const float* __restrict__ s1, const float* __restrict__ s2,
    const float* __restrict__ s3, const float* __restrict__ s4, const float* __restrict__ s5,
    const float* __restrict__ s6,
    unsigned short* __restrict__ d0, unsigned short* __restrict__ d1, unsigned short* __restrict__ d2,
    unsigned short* __restrict__ d3, unsigned short* __restrict__ d4, unsigned short* __restrict__ d5,
    unsigned short* __restrict__ d6) {
  const int z = blockIdx.y;
  const float* s = (z == 0) ? s0 : (z == 1) ? s1 : (z == 2) ? s2 : (z == 3) ? s3
                 : (z == 4) ? s4 : (z == 5) ? s5 : s6;
  unsigned short* d = (z == 0) ? d0 : (z == 1) ? d1 : (z == 2) ? d2 : (z == 3) ? d3
                    : (z == 4) ? d4 : (z == 5) ? d5 : d6;
  const size_t n = (z < 3) ? (size_t)PP * DDIM : (size_t)DDIM * DDIM;
  const size_t i = ((size_t)blockIdx.x * 256 + threadIdx.x) * 8;
  if (i >= n) return;
  const float4 x0 = *(const float4*)(s + i);
  const float4 x1 = *(const float4*)(s + i + 4);
  bf16x8 o;
  o[0] = f2bf(x0.x); o[1] = f2bf(x0.y); o[2] = f2bf(x0.z); o[3] = f2bf(x0.w);
  o[4] = f2bf(x1.x); o[5] = f2bf(x1.y); o[6] = f2bf(x1.z); o[7] = f2bf(x1.w);
  *(bf16x8*)(d + i) = o;
}

// ---------------- GEMM (m97 structure): Y[2048][1024] = A @ B^T + bias ------
template<int YF32>
__device__ __forceinline__ void gemm128_body(
    const unsigned short* __restrict__ A, const unsigned short* __restrict__ B,
    const float* __restrict__ bias, void* __restrict__ Yv) {
  __shared__ unsigned short As[4096];   // 128x32 linear
  __shared__ unsigned short Bs[4096];
  const int tid = threadIdx.x, lane = tid & 63, w = tid >> 6;
  const int m0 = blockIdx.y * 128, n0 = blockIdx.x * 128;
  const int g = lane >> 4, ln = lane & 15;
  const int wm = (w >> 1) * 64, wn = (w & 1) * 64;
  const int sr = tid >> 2, sc = (tid & 3) * 8;
  unsigned short* asd0 = As + w * 512;
  unsigned short* asd1 = As + 2048 + w * 512;
  unsigned short* bsd0 = Bs + w * 512;
  unsigned short* bsd1 = Bs + 2048 + w * 512;
  f32x4 acc[4][4] = {};
  for (int k0 = 0; k0 < DDIM; k0 += 32) {
    __syncthreads();
    gld_lds16(A + (size_t)(m0 + sr) * DDIM + k0 + sc, asd0);
    gld_lds16(A + (size_t)(m0 + 64 + sr) * DDIM + k0 + sc, asd1);
    gld_lds16(B + (size_t)(n0 + sr) * DDIM + k0 + sc, bsd0);
    gld_lds16(B + (size_t)(n0 + 64 + sr) * DDIM + k0 + sc, bsd1);
    __syncthreads();
    bf16x8 a[4], b[4];
#pragma unroll
    for (int mi = 0; mi < 4; ++mi) a[mi] = *(const bf16x8*)&As[(wm + mi * 16 + ln) * 32 + g * 8];
#pragma unroll
    for (int ni = 0; ni < 4; ++ni) b[ni] = *(const bf16x8*)&Bs[(wn + ni * 16 + ln) * 32 + g * 8];
#pragma unroll
    for (int mi = 0; mi < 4; ++mi)
#pragma unroll
      for (int ni = 0; ni < 4; ++ni)
        acc[mi][ni] = __builtin_amdgcn_mfma_f32_16x16x32_bf16(a[mi], b[ni], acc[mi][ni], 0, 0, 0);
  }
#pragma unroll
  for (int mi = 0; mi < 4; ++mi)
#pragma unroll
    for (int ni = 0; ni < 4; ++ni) {
      const int n = n0 + wn + ni * 16 + ln;
      const float bs = bias[n];
#pragma unroll
      for (int r = 0; r < 4; ++r) {
        const int m = m0 + wm + mi * 16 + g * 4 + r;
        const float v = acc[mi][ni][r] + bs;
        if (YF32) ((float*)Yv)[(size_t)m * DDIM + n] = v;
        else ((unsigned short*)Yv)[(size_t)m * DDIM + n] = (unsigned short)f2bf(v);
      }
    }
}

__global__ __launch_bounds__(256, 2) void qkv_gemm(
    const unsigned short* __restrict__ Qb, const unsigned short* __restrict__ Kb,
    const unsigned short* __restrict__ Vb,
    const unsigned short* __restrict__ Wq, const unsigned short* __restrict__ Wk,
    const unsigned short* __restrict__ Wv,
    const float* __restrict__ bq, const float* __restrict__ bk, const float* __restrict__ bv,
    unsigned short* __restrict__ qo, unsigned short* __restrict__ ko,
    unsigned short* __restrict__ vo) {
  const int z = blockIdx.z;
  gemm128_body<0>((z == 0) ? Qb : (z == 1) ? Kb : Vb,
                  (z == 0) ? Wq : (z == 1) ? Wk : Wv,
                  (z == 0) ? bq : (z == 1) ? bk : bv,
                  (z == 0) ? qo : (z == 1) ? ko : vo);
}

__global__ __launch_bounds__(256, 2) void out_gemm(
    const unsigned short* __restrict__ A, const unsigned short* __restrict__ B,
    const float* __restrict__ bias, float* __restrict__ Y) {
  gemm128_body<1>(A, B, bias, Y);
}

// ---------------- V transpose: vT[d][s] = vb[s][d] ----------------
__global__ __launch_bounds__(256) void transpose_v(
    const unsigned short* __restrict__ vb, unsigned short* __restrict__ vT) {
  __shared__ unsigned short t[64][72];
  const int tid = threadIdx.x;
  const int sb = blockIdx.x * 64, db = blockIdx.y * 64;
#pragma unroll
  for (int pass = 0; pass < 2; ++pass) {
    const int e = pass * 2048 + tid * 8;
    const int r = e >> 6, c = e & 63;
    *(bf16x8*)&t[r][c] = *(const bf16x8*)(vb + (size_t)(sb + r) * DDIM + db + c);
  }
  __syncthreads();
#pragma unroll
  for (int pass = 0; pass < 2; ++pass) {
    const int e = pass * 2048 + tid * 8;
    const int r = e >> 6, c = e & 63;   // r: d row, c: s col
    bf16x8 ov;
#pragma unroll
    for (int u = 0; u < 8; ++u) ov[u] = (short)t[c + u][r];
    *(bf16x8*)(vT + (size_t)(db + r) * SSEQ + sb + c) = ov;
  }
}

// ---------------- scorespv v5 (R16 champion): K staged via async gld_lds ----
// grid 512; block 256 = 4 waves, wave = 16 rows. K tile (128x64 bf16 = 16KB)
// staged once per block per tile via global_load_lds, dbuf, issued one tile
// ahead; XOR-swizzled via pre-swizzled global source (rule #21). XCD swizzle:
// h = 2*(b&7) + ((b>>3)&1) -> per-XCD K/V working set 1MB (L2-resident).
__global__ __launch_bounds__(256, 2) void scorespv(
    const unsigned short* __restrict__ qb, const unsigned short* __restrict__ kb,
    const unsigned short* __restrict__ vT,
    const float* __restrict__ prev, const float* __restrict__ ch_gate,
    float* __restrict__ raw, float* __restrict__ l_row,
    unsigned short* __restrict__ ctx) {
  __shared__ float Rs[4][16][132];          // 33.8KB
  __shared__ float lS[4][16];
  __shared__ unsigned short Ks[2][8192];    // 2 x (128 rows x 64 cols) = 32KB
  const int tid = threadIdx.x, lane = tid & 63, w = tid >> 6;
  const int b = blockIdx.x;
  const int h = (b & 7) * 2 + ((b >> 3) & 1);   // XCD-local head pairs
  const int pt = b >> 4;                         // 0..31
  const int p0 = pt * 64, wr = w * 16;
  const int g = lane >> 4, ln = lane & 15;
  const int myp = p0 + wr + ln;
  const int pc = p0 >> 8;

  const int strow = w * 32 + (lane >> 3);
  const int scol = (((lane & 7) << 4) ^ ((lane >> 3) << 4)) >> 1;

  bf16x8 aq[2];
#pragma unroll
  for (int ks = 0; ks < 2; ++ks)
    aq[ks] = *(const bf16x8*)(qb + (size_t)myp * DDIM + h * DH + ks * 32 + g * 8);

  f32x4 U[4] = {};
  float lsum = 0.f;
  const size_t rowb = ((size_t)myp * NH + h) * SSEQ;

  // prologue: stage K tile 0 + prefetch prev tile 0
#pragma unroll
  for (int i = 0; i < 4; ++i)
    gld_lds16(kb + (size_t)(strow + i * 8) * DDIM + h * DH + scol,
              &Ks[0][(w * 32 + i * 8) * 64]);
  f32x4 pv[8];
#pragma unroll
  for (int ks = 0; ks < 4; ++ks) {
    pv[2 * ks]     = __builtin_nontemporal_load((const f32x4*)(prev + rowb + ks * 32 + g * 8));
    pv[2 * ks + 1] = __builtin_nontemporal_load((const f32x4*)(prev + rowb + ks * 32 + g * 8 + 4));
  }
  __syncthreads();   // K tile 0 staged

  for (int t = 0; t < 16; ++t) {
    const int s0 = t * 128;
    const float gate = (ch_gate[pc * 8 + (s0 >> 8)] >= 0.f) ? 1.f : 0.f;
    if (t < 15) {
#pragma unroll
      for (int i = 0; i < 4; ++i)
        gld_lds16(kb + (size_t)(s0 + 128 + strow + i * 8) * DDIM + h * DH + scol,
                  &Ks[(t + 1) & 1][(w * 32 + i * 8) * 64]);
    }
    const char* Kbuf = (const char*)Ks[t & 1];
#pragma unroll
    for (int half = 0; half < 2; ++half) {
      f32x4 acc[4] = {};
#pragma unroll
      for (int ks = 0; ks < 2; ++ks)
#pragma unroll
        for (int nj = 0; nj < 4; ++nj) {
          const int row = half * 64 + nj * 16 + ln;
          const bf16x8 bk = *(const bf16x8*)(Kbuf + row * 128 + ((ks * 64 + g * 16) ^ ((ln & 7) << 4)));
          acc[nj] = __builtin_amdgcn_mfma_f32_16x16x32_bf16(aq[ks], bk, acc[nj], 0, 0, 0);
        }
#pragma unroll
      for (int nj = 0; nj < 4; ++nj)
#pragma unroll
        for (int r = 0; r < 4; ++r)
          Rs[w][g * 4 + r][half * 64 + nj * 16 + ln] = acc[nj][r];
    }
    f32x4 pvn[8];
    if (t < 15) {
#pragma unroll
      for (int ks = 0; ks < 4; ++ks) {
        pvn[2 * ks]     = __builtin_nontemporal_load((const f32x4*)(prev + rowb + s0 + 128 + ks * 32 + g * 8));
        pvn[2 * ks + 1] = __builtin_nontemporal_load((const f32x4*)(prev + rowb + s0 + 128 + ks * 32 + g * 8 + 4));
      }
    }
    f32x4 v[8];
#pragma unroll
    for (int ks = 0; ks < 4; ++ks)
#pragma unroll
      for (int hf = 0; hf < 2; ++hf) {
        const int c0 = ks * 32 + g * 8 + hf * 4;
        const f32x4 sc = *(const f32x4*)&Rs[w][ln][c0];
        f32x4 vv;
        vv[0] = fmaf(sc[0], 0.125f, pv[ks * 2 + hf][0]) * gate;
        vv[1] = fmaf(sc[1], 0.125f, pv[ks * 2 + hf][1]) * gate;
        vv[2] = fmaf(sc[2], 0.125f, pv[ks * 2 + hf][2]) * gate;
        vv[3] = fmaf(sc[3], 0.125f, pv[ks * 2 + hf][3]) * gate;
        v[ks * 2 + hf] = vv;
        *(f32x4*)(raw + rowb + s0 + c0) = vv;   // normal store -> L3 for attn_norm
      }
    if (s0 <= p0 + wr + 15) {
      bf16x8 pa[4];
#pragma unroll
      for (int ks = 0; ks < 4; ++ks) {
        const int cb = s0 + ks * 32 + g * 8;
        float e[8];
#pragma unroll
        for (int j = 0; j < 4; ++j) {
          e[j]     = (cb + j     <= myp) ? __expf(v[2 * ks][j])     : 0.f;
          e[j + 4] = (cb + j + 4 <= myp) ? __expf(v[2 * ks + 1][j]) : 0.f;
        }
        lsum += ((e[0] + e[1]) + (e[2] + e[3])) + ((e[4] + e[5]) + (e[6] + e[7]));
        bf16x8 pk;
#pragma unroll
        for (int j = 0; j < 8; ++j) pk[j] = f2bf(e[j]);
        pa[ks] = pk;
      }
#pragma unroll
      for (int nj = 0; nj < 4; ++nj) {
        const size_t vb0 = (size_t)(h * DH + nj * 16 + ln) * SSEQ + s0;
        const bf16x8 b0 = *(const bf16x8*)(vT + vb0 + g * 8);
        const bf16x8 b1 = *(const bf16x8*)(vT + vb0 + 32 + g * 8);
        const bf16x8 b2 = *(const bf16x8*)(vT + vb0 + 64 + g * 8);
        const bf16x8 b3 = *(const bf16x8*)(vT + vb0 + 96 + g * 8);
        U[nj] = __builtin_amdgcn_mfma_f32_16x16x32_bf16(pa[0], b0, U[nj], 0, 0, 0);
        U[nj] = __builtin_amdgcn_mfma_f32_16x16x32_bf16(pa[1], b1, U[nj], 0, 0, 0);
        U[nj] = __builtin_amdgcn_mfma_f32_16x16x32_bf16(pa[2], b2, U[nj], 0, 0, 0);
        U[nj] = __builtin_amdgcn_mfma_f32_16x16x32_bf16(pa[3], b3, U[nj], 0, 0, 0);
      }
    }
    if (t < 15) {
#pragma unroll
      for (int i = 0; i < 8; ++i) pv[i] = pvn[i];
    }
    __syncthreads();   // next K tile staged; all waves done with Ks[t&1]
  }
  lsum += __shfl_xor(lsum, 16);
  lsum += __shfl_xor(lsum, 32);
  if (g == 0) {
    lS[w][ln] = lsum;
    l_row[h * PP + myp] = lsum;
  }
  float il4[4];
#pragma unroll
  for (int r = 0; r < 4; ++r) il4[r] = 1.f / lS[w][g * 4 + r];
#pragma unroll
  for (int nj = 0; nj < 4; ++nj)
#pragma unroll
    for (int r = 0; r < 4; ++r) {
      const int p = p0 + wr + g * 4 + r;
      ctx[(size_t)p * DDIM + h * DH + nj * 16 + ln] = (unsigned short)f2bf(U[nj][r] * il4[r]);
    }
}

// ---------------- attn_norm: attn = exp(raw)/l (causal), zeros elsewhere ----
__global__ __launch_bounds__(256) void attn_norm(
    const float* __restrict__ raw, const float* __restrict__ l_row,
    float* __restrict__ attn) {
  const int b = blockIdx.x;
  const int lo = b & 255, k8 = b >> 8;
  const int h = lo & 15, ptb = lo >> 4;
  const int pt = ptb + 16 * k8;                 // 0..127
  const int p0 = pt * 16;
  __shared__ float ilS[16];
  if (threadIdx.x < 16) ilS[threadIdx.x] = 1.f / l_row[h * PP + p0 + threadIdx.x];
  __syncthreads();
  const int limit = ((p0 + 16 + 127) >> 7) << 7;
  const int col = threadIdx.x * 4;
  for (int c0 = 0; c0 < SSEQ; c0 += 1024) {
    const int c = c0 + col;
#pragma unroll 4
    for (int r = 0; r < 16; ++r) {
      const int p = p0 + r;
      const size_t base = ((size_t)p * NH + h) * SSEQ + c;
      f32x4 av = {0.f, 0.f, 0.f, 0.f};
      if (c < limit) {
        const float il = ilS[r];
        const f32x4 rv = *(const f32x4*)(raw + base);
        av[0] = (c + 0 <= p) ? __expf(rv[0]) * il : 0.f;
        av[1] = (c + 1 <= p) ? __expf(rv[1]) * il : 0.f;
        av[2] = (c + 2 <= p) ? __expf(rv[2]) * il : 0.f;
        av[3] = (c + 3 <= p) ? __expf(rv[3]) * il : 0.f;
      }
      __builtin_nontemporal_store(av, (f32x4*)(attn + base));
    }
  }
}

extern "C" void kernel_launch(void* const* d_in, const int* in_sizes, int n_in,
                              void* d_out, int out_size, void* d_ws, size_t ws_size,
                              hipStream_t stream) {
  (void)in_sizes; (void)n_in; (void)out_size; (void)ws_size;
  const float* Q    = (const float*)d_in[0];
  const float* K    = (const float*)d_in[1];
  const float* V    = (const float*)d_in[2];
  const float* prev = (const float*)d_in[3];
  const float* Wq   = (const float*)d_in[4];
  const float* bq   = (const float*)d_in[5];
  const float* Wk   = (const float*)d_in[6];
  const float* bk   = (const float*)d_in[7];
  const float* Wv   = (const float*)d_in[8];
  const float* bv   = (const float*)d_in[9];
  const float* Wo   = (const float*)d_in[10];
  const float* bo   = (const float*)d_in[11];
  const float* ch_gate = (const float*)d_in[12];

  float* out  = (float*)d_out;                       // (2048,1024)
  float* attn = out + (size_t)PP * DDIM;             // (2048,16,2048)
  float* raw  = attn + (size_t)PP * NH * SSEQ;       // (2048,16,2048)

  // ws layout (~36MB, lifetime-overlapped):
  unsigned short* ws16 = (unsigned short*)d_ws;
  unsigned short* qb   = ws16;                       // 2M elems each
  unsigned short* kb   = qb + 2097152;
  unsigned short* vb   = kb + 2097152;
  unsigned short* vT   = vb + 2097152;
  unsigned short* buf5 = vT + 2097152;               // Qbf -> ctx
  unsigned short* buf6 = buf5 + 2097152;             // Kbf
  unsigned short* buf7 = buf6 + 2097152;             // Vbf
  float* l_row = (float*)(buf7 + 2097152);           // (16,2048) f32
  unsigned short* wqb = (unsigned short*)(l_row + 32768);   // 1M elems each
  unsigned short* wkb = wqb + 1048576;
  unsigned short* wvb = wkb + 1048576;
  unsigned short* wob = wvb + 1048576;

  unsigned short* Qbf = buf5;   // dead after qkv_gemm; reused as ctx
  unsigned short* Kbf = buf6;
  unsigned short* Vbf = buf7;
  unsigned short* ctx = buf5;

  dim3 blk(256);
  cvt7<<<dim3(1024, 7), blk, 0, stream>>>(
      Q, K, V, Wq, Wk, Wv, Wo, Qbf, Kbf, Vbf, wqb, wkb, wvb, wob);
  qkv_gemm<<<dim3(DDIM / 128, PP / 128, 3), blk, 0, stream>>>(
      Qbf, Kbf, Vbf, wqb, wkb, wvb, bq, bk, bv, qb, kb, vb);
  transpose_v<<<dim3(SSEQ / 64, DDIM / 64), blk, 0, stream>>>(vb, vT);
  scorespv<<<dim3(512), blk, 0, stream>>>(
      qb, kb, vT, prev, ch_gate, raw, l_row, ctx);
  attn_norm<<<dim3(2048), blk, 0, stream>>>(raw, l_row, attn);
  out_gemm<<<dim3(DDIM / 128, PP / 128), blk, 0, stream>>>(ctx, wob, bo, out);
}

// Round 20
// 278.249 us; speedup vs baseline: 1.0696x; 1.0310x over previous
//
#include <hip/hip_runtime.h>

#define PP 2048     // P (pred rows)
#define SSEQ 2048   // S (key rows)
#define DDIM 1024   // D
#define NH 16       // heads
#define DH 64       // head dim

typedef __attribute__((ext_vector_type(4))) float f32x4;
typedef __attribute__((ext_vector_type(8))) short bf16x8;
typedef __attribute__((ext_vector_type(4))) short bf16x4;

__device__ __forceinline__ short f2bf(float f) {
  unsigned u = __builtin_bit_cast(unsigned, f);
  u += 0x7FFFu + ((u >> 16) & 1u);   // RNE
  return (short)(u >> 16);
}
__device__ __forceinline__ float bf2f(unsigned short u) {
  return __builtin_bit_cast(float, ((unsigned)u) << 16);
}
__device__ __forceinline__ void gld_lds16(const void* g, void* l) {
  __builtin_amdgcn_global_load_lds(
      (const __attribute__((address_space(1))) void*)g,
      (__attribute__((address_space(3))) void*)l, 16, 0, 0);
}

// ---------------- bf16 conversion: 7 buffers in one launch ----------------
__global__ __launch_bounds__(256) void cvt7(
    const float* __restrict__ s0, const float* __restrict__ s1, const float* __restrict__ s2,
    const float* __restrict__ s3, const float* __restrict__ s4, const float* __restrict__ s5,
    const float* __restrict__ s6,
    unsigned short* __restrict__ d0, unsigned short* __restrict__ d1, unsigned short* __restrict__ d2,
    unsigned short* __restrict__ d3, unsigned short* __restrict__ d4, unsigned short* __restrict__ d5,
    unsigned short* __restrict__ d6) {
  const int z = blockIdx.y;
  const float* s = (z == 0) ? s0 : (z == 1) ? s1 : (z == 2) ? s2 : (z == 3) ? s3
                 : (z == 4) ? s4 : (z == 5) ? s5 : s6;
  unsigned short* d = (z == 0) ? d0 : (z == 1) ? d1 : (z == 2) ? d2 : (z == 3) ? d3
                    : (z == 4) ? d4 : (z == 5) ? d5 : d6;
  const size_t n = (z < 3) ? (size_t)PP * DDIM : (size_t)DDIM * DDIM;
  const size_t i = ((size_t)blockIdx.x * 256 + threadIdx.x) * 8;
  if (i >= n) return;
  const float4 x0 = *(const float4*)(s + i);
  const float4 x1 = *(const float4*)(s + i + 4);
  bf16x8 o;
  o[0] = f2bf(x0.x); o[1] = f2bf(x0.y); o[2] = f2bf(x0.z); o[3] = f2bf(x0.w);
  o[4] = f2bf(x1.x); o[5] = f2bf(x1.y); o[6] = f2bf(x1.z); o[7] = f2bf(x1.w);
  *(bf16x8*)(d + i) = o;
}

// ---------------- GEMM (m97 structure): Y[2048][1024] = A @ B^T + bias ------
template<int YF32>
__device__ __forceinline__ void gemm128_body(
    const unsigned short* __restrict__ A, const unsigned short* __restrict__ B,
    const float* __restrict__ bias, void* __restrict__ Yv) {
  __shared__ unsigned short As[4096];   // 128x32 linear
  __shared__ unsigned short Bs[4096];
  const int tid = threadIdx.x, lane = tid & 63, w = tid >> 6;
  const int m0 = blockIdx.y * 128, n0 = blockIdx.x * 128;
  const int g = lane >> 4, ln = lane & 15;
  const int wm = (w >> 1) * 64, wn = (w & 1) * 64;
  const int sr = tid >> 2, sc = (tid & 3) * 8;
  unsigned short* asd0 = As + w * 512;
  unsigned short* asd1 = As + 2048 + w * 512;
  unsigned short* bsd0 = Bs + w * 512;
  unsigned short* bsd1 = Bs + 2048 + w * 512;
  f32x4 acc[4][4] = {};
  for (int k0 = 0; k0 < DDIM; k0 += 32) {
    __syncthreads();
    gld_lds16(A + (size_t)(m0 + sr) * DDIM + k0 + sc, asd0);
    gld_lds16(A + (size_t)(m0 + 64 + sr) * DDIM + k0 + sc, asd1);
    gld_lds16(B + (size_t)(n0 + sr) * DDIM + k0 + sc, bsd0);
    gld_lds16(B + (size_t)(n0 + 64 + sr) * DDIM + k0 + sc, bsd1);
    __syncthreads();
    bf16x8 a[4], b[4];
#pragma unroll
    for (int mi = 0; mi < 4; ++mi) a[mi] = *(const bf16x8*)&As[(wm + mi * 16 + ln) * 32 + g * 8];
#pragma unroll
    for (int ni = 0; ni < 4; ++ni) b[ni] = *(const bf16x8*)&Bs[(wn + ni * 16 + ln) * 32 + g * 8];
#pragma unroll
    for (int mi = 0; mi < 4; ++mi)
#pragma unroll
      for (int ni = 0; ni < 4; ++ni)
        acc[mi][ni] = __builtin_amdgcn_mfma_f32_16x16x32_bf16(a[mi], b[ni], acc[mi][ni], 0, 0, 0);
  }
#pragma unroll
  for (int mi = 0; mi < 4; ++mi)
#pragma unroll
    for (int ni = 0; ni < 4; ++ni) {
      const int n = n0 + wn + ni * 16 + ln;
      const float bs = bias[n];
#pragma unroll
      for (int r = 0; r < 4; ++r) {
        const int m = m0 + wm + mi * 16 + g * 4 + r;
        const float v = acc[mi][ni][r] + bs;
        if (YF32) ((float*)Yv)[(size_t)m * DDIM + n] = v;
        else ((unsigned short*)Yv)[(size_t)m * DDIM + n] = (unsigned short)f2bf(v);
      }
    }
}

__global__ __launch_bounds__(256, 2) void qkv_gemm(
    const unsigned short* __restrict__ Qb, const unsigned short* __restrict__ Kb,
    const unsigned short* __restrict__ Vb,
    const unsigned short* __restrict__ Wq, const unsigned short* __restrict__ Wk,
    const unsigned short* __restrict__ Wv,
    const float* __restrict__ bq, const float* __restrict__ bk, const float* __restrict__ bv,
    unsigned short* __restrict__ qo, unsigned short* __restrict__ ko,
    unsigned short* __restrict__ vo) {
  const int z = blockIdx.z;
  gemm128_body<0>((z == 0) ? Qb : (z == 1) ? Kb : Vb,
                  (z == 0) ? Wq : (z == 1) ? Wk : Wv,
                  (z == 0) ? bq : (z == 1) ? bk : bv,
                  (z == 0) ? qo : (z == 1) ? ko : vo);
}

__global__ __launch_bounds__(256, 2) void out_gemm(
    const unsigned short* __restrict__ A, const unsigned short* __restrict__ B,
    const float* __restrict__ bias, float* __restrict__ Y) {
  gemm128_body<1>(A, B, bias, Y);
}

// ---------------- V transpose: vT[d][s] = vb[s][d] ----------------
__global__ __launch_bounds__(256) void transpose_v(
    const unsigned short* __restrict__ vb, unsigned short* __restrict__ vT) {
  __shared__ unsigned short t[64][72];
  const int tid = threadIdx.x;
  const int sb = blockIdx.x * 64, db = blockIdx.y * 64;
#pragma unroll
  for (int pass = 0; pass < 2; ++pass) {
    const int e = pass * 2048 + tid * 8;
    const int r = e >> 6, c = e & 63;
    *(bf16x8*)&t[r][c] = *(const bf16x8*)(vb + (size_t)(sb + r) * DDIM + db + c);
  }
  __syncthreads();
#pragma unroll
  for (int pass = 0; pass < 2; ++pass) {
    const int e = pass * 2048 + tid * 8;
    const int r = e >> 6, c = e & 63;   // r: d row, c: s col
    bf16x8 ov;
#pragma unroll
    for (int u = 0; u < 8; ++u) ov[u] = (short)t[c + u][r];
    *(bf16x8*)(vT + (size_t)(db + r) * SSEQ + sb + c) = ov;
  }
}

// ---------------- scorespv v7: R16 + triangle-paired pt mapping -------------
// grid 512; block 256 = 4 waves, wave = 16 rows. K staged via gld_lds (dbuf,
// swizzled per rule #21). XCD head-locality: h = 2*(b&7) + ((b>>3)&1) (same
// for b and b+256). Triangle pairing: pt = b<256 ? b>>4 : 31-(b>>4), so the
// same-CU pair (b, b+256) has constant causal-PV work (33 tiles) AND shares
// its head's K/V in L2/L1.
__global__ __launch_bounds__(256, 2) void scorespv(
    const unsigned short* __restrict__ qb, const unsigned short* __restrict__ kb,
    const unsigned short* __restrict__ vT,
    const float* __restrict__ prev, const float* __restrict__ ch_gate,
    float* __restrict__ raw, float* __restrict__ l_row,
    unsigned short* __restrict__ ctx) {
  __shared__ float Rs[4][16][132];          // 33.8KB
  __shared__ float lS[4][16];
  __shared__ unsigned short Ks[2][8192];    // 2 x (128 rows x 64 cols) = 32KB
  const int tid = threadIdx.x, lane = tid & 63, w = tid >> 6;
  const int b = blockIdx.x;
  const int h = (b & 7) * 2 + ((b >> 3) & 1);            // XCD-local head pairs
  const int ptb = (b & 255) >> 4;
  const int pt = (b < 256) ? ptb : (31 - ptb);           // triangle pairing
  const int p0 = pt * 64, wr = w * 16;
  const int g = lane >> 4, ln = lane & 15;
  const int myp = p0 + wr + ln;
  const int pc = p0 >> 8;

  const int strow = w * 32 + (lane >> 3);
  const int scol = (((lane & 7) << 4) ^ ((lane >> 3) << 4)) >> 1;

  bf16x8 aq[2];
#pragma unroll
  for (int ks = 0; ks < 2; ++ks)
    aq[ks] = *(const bf16x8*)(qb + (size_t)myp * DDIM + h * DH + ks * 32 + g * 8);

  f32x4 U[4] = {};
  float lsum = 0.f;
  const size_t rowb = ((size_t)myp * NH + h) * SSEQ;

  // prologue: stage K tile 0 + prefetch prev tile 0
#pragma unroll
  for (int i = 0; i < 4; ++i)
    gld_lds16(kb + (size_t)(strow + i * 8) * DDIM + h * DH + scol,
              &Ks[0][(w * 32 + i * 8) * 64]);
  f32x4 pv[8];
#pragma unroll
  for (int ks = 0; ks < 4; ++ks) {
    pv[2 * ks]     = __builtin_nontemporal_load((const f32x4*)(prev + rowb + ks * 32 + g * 8));
    pv[2 * ks + 1] = __builtin_nontemporal_load((const f32x4*)(prev + rowb + ks * 32 + g * 8 + 4));
  }
  __syncthreads();   // K tile 0 staged

  for (int t = 0; t < 16; ++t) {
    const int s0 = t * 128;
    const float gate = (ch_gate[pc * 8 + (s0 >> 8)] >= 0.f) ? 1.f : 0.f;
    if (t < 15) {
#pragma unroll
      for (int i = 0; i < 4; ++i)
        gld_lds16(kb + (size_t)(s0 + 128 + strow + i * 8) * DDIM + h * DH + scol,
                  &Ks[(t + 1) & 1][(w * 32 + i * 8) * 64]);
    }
    const char* Kbuf = (const char*)Ks[t & 1];
#pragma unroll
    for (int half = 0; half < 2; ++half) {
      f32x4 acc[4] = {};
#pragma unroll
      for (int ks = 0; ks < 2; ++ks)
#pragma unroll
        for (int nj = 0; nj < 4; ++nj) {
          const int row = half * 64 + nj * 16 + ln;
          const bf16x8 bk = *(const bf16x8*)(Kbuf + row * 128 + ((ks * 64 + g * 16) ^ ((ln & 7) << 4)));
          acc[nj] = __builtin_amdgcn_mfma_f32_16x16x32_bf16(aq[ks], bk, acc[nj], 0, 0, 0);
        }
#pragma unroll
      for (int nj = 0; nj < 4; ++nj)
#pragma unroll
        for (int r = 0; r < 4; ++r)
          Rs[w][g * 4 + r][half * 64 + nj * 16 + ln] = acc[nj][r];
    }
    f32x4 pvn[8];
    if (t < 15) {
#pragma unroll
      for (int ks = 0; ks < 4; ++ks) {
        pvn[2 * ks]     = __builtin_nontemporal_load((const f32x4*)(prev + rowb + s0 + 128 + ks * 32 + g * 8));
        pvn[2 * ks + 1] = __builtin_nontemporal_load((const f32x4*)(prev + rowb + s0 + 128 + ks * 32 + g * 8 + 4));
      }
    }
    f32x4 v[8];
#pragma unroll
    for (int ks = 0; ks < 4; ++ks)
#pragma unroll
      for (int hf = 0; hf < 2; ++hf) {
        const int c0 = ks * 32 + g * 8 + hf * 4;
        const f32x4 sc = *(const f32x4*)&Rs[w][ln][c0];
        f32x4 vv;
        vv[0] = fmaf(sc[0], 0.125f, pv[ks * 2 + hf][0]) * gate;
        vv[1] = fmaf(sc[1], 0.125f, pv[ks * 2 + hf][1]) * gate;
        vv[2] = fmaf(sc[2], 0.125f, pv[ks * 2 + hf][2]) * gate;
        vv[3] = fmaf(sc[3], 0.125f, pv[ks * 2 + hf][3]) * gate;
        v[ks * 2 + hf] = vv;
        *(f32x4*)(raw + rowb + s0 + c0) = vv;   // normal store -> L3 for attn_norm
      }
    if (s0 <= p0 + wr + 15) {
      bf16x8 pa[4];
#pragma unroll
      for (int ks = 0; ks < 4; ++ks) {
        const int cb = s0 + ks * 32 + g * 8;
        float e[8];
#pragma unroll
        for (int j = 0; j < 4; ++j) {
          e[j]     = (cb + j     <= myp) ? __expf(v[2 * ks][j])     : 0.f;
          e[j + 4] = (cb + j + 4 <= myp) ? __expf(v[2 * ks + 1][j]) : 0.f;
        }
        lsum += ((e[0] + e[1]) + (e[2] + e[3])) + ((e[4] + e[5]) + (e[6] + e[7]));
        bf16x8 pk;
#pragma unroll
        for (int j = 0; j < 8; ++j) pk[j] = f2bf(e[j]);
        pa[ks] = pk;
      }
#pragma unroll
      for (int nj = 0; nj < 4; ++nj) {
        const size_t vb0 = (size_t)(h * DH + nj * 16 + ln) * SSEQ + s0;
        const bf16x8 b0 = *(const bf16x8*)(vT + vb0 + g * 8);
        const bf16x8 b1 = *(const bf16x8*)(vT + vb0 + 32 + g * 8);
        const bf16x8 b2 = *(const bf16x8*)(vT + vb0 + 64 + g * 8);
        const bf16x8 b3 = *(const bf16x8*)(vT + vb0 + 96 + g * 8);
        U[nj] = __builtin_amdgcn_mfma_f32_16x16x32_bf16(pa[0], b0, U[nj], 0, 0, 0);
        U[nj] = __builtin_amdgcn_mfma_f32_16x16x32_bf16(pa[1], b1, U[nj], 0, 0, 0);
        U[nj] = __builtin_amdgcn_mfma_f32_16x16x32_bf16(pa[2], b2, U[nj], 0, 0, 0);
        U[nj] = __builtin_amdgcn_mfma_f32_16x16x32_bf16(pa[3], b3, U[nj], 0, 0, 0);
      }
    }
    if (t < 15) {
#pragma unroll
      for (int i = 0; i < 8; ++i) pv[i] = pvn[i];
    }
    __syncthreads();   // next K tile staged; all waves done with Ks[t&1]
  }
  lsum += __shfl_xor(lsum, 16);
  lsum += __shfl_xor(lsum, 32);
  if (g == 0) {
    lS[w][ln] = lsum;
    l_row[h * PP + myp] = lsum;
  }
  float il4[4];
#pragma unroll
  for (int r = 0; r < 4; ++r) il4[r] = 1.f / lS[w][g * 4 + r];
#pragma unroll
  for (int nj = 0; nj < 4; ++nj)
#pragma unroll
    for (int r = 0; r < 4; ++r) {
      const int p = p0 + wr + g * 4 + r;
      ctx[(size_t)p * DDIM + h * DH + nj * 16 + ln] = (unsigned short)f2bf(U[nj][r] * il4[r]);
    }
}

// ---------------- attn_norm: attn = exp(raw)/l (causal), zeros elsewhere ----
__global__ __launch_bounds__(256) void attn_norm(
    const float* __restrict__ raw, const float* __restrict__ l_row,
    float* __restrict__ attn) {
  const int b = blockIdx.x;
  const int lo = b & 255, k8 = b >> 8;
  const int h = lo & 15, ptb = lo >> 4;
  const int pt = ptb + 16 * k8;                 // 0..127
  const int p0 = pt * 16;
  __shared__ float ilS[16];
  if (threadIdx.x < 16) ilS[threadIdx.x] = 1.f / l_row[h * PP + p0 + threadIdx.x];
  __syncthreads();
  const int limit = ((p0 + 16 + 127) >> 7) << 7;
  const int col = threadIdx.x * 4;
  for (int c0 = 0; c0 < SSEQ; c0 += 1024) {
    const int c = c0 + col;
#pragma unroll 4
    for (int r = 0; r < 16; ++r) {
      const int p = p0 + r;
      const size_t base = ((size_t)p * NH + h) * SSEQ + c;
      f32x4 av = {0.f, 0.f, 0.f, 0.f};
      if (c < limit) {
        const float il = ilS[r];
        const f32x4 rv = *(const f32x4*)(raw + base);
        av[0] = (c + 0 <= p) ? __expf(rv[0]) * il : 0.f;
        av[1] = (c + 1 <= p) ? __expf(rv[1]) * il : 0.f;
        av[2] = (c + 2 <= p) ? __expf(rv[2]) * il : 0.f;
        av[3] = (c + 3 <= p) ? __expf(rv[3]) * il : 0.f;
      }
      __builtin_nontemporal_store(av, (f32x4*)(attn + base));
    }
  }
}

extern "C" void kernel_launch(void* const* d_in, const int* in_sizes, int n_in,
                              void* d_out, int out_size, void* d_ws, size_t ws_size,
                              hipStream_t stream) {
  (void)in_sizes; (void)n_in; (void)out_size; (void)ws_size;
  const float* Q    = (const float*)d_in[0];
  const float* K    = (const float*)d_in[1];
  const float* V    = (const float*)d_in[2];
  const float* prev = (const float*)d_in[3];
  const float* Wq   = (const float*)d_in[4];
  const float* bq   = (const float*)d_in[5];
  const float* Wk   = (const float*)d_in[6];
  const float* bk   = (const float*)d_in[7];
  const float* Wv   = (const float*)d_in[8];
  const float* bv   = (const float*)d_in[9];
  const float* Wo   = (const float*)d_in[10];
  const float* bo   = (const float*)d_in[11];
  const float* ch_gate = (const float*)d_in[12];

  float* out  = (float*)d_out;                       // (2048,1024)
  float* attn = out + (size_t)PP * DDIM;             // (2048,16,2048)
  float* raw  = attn + (size_t)PP * NH * SSEQ;       // (2048,16,2048)

  // ws layout (~36MB, lifetime-overlapped):
  unsigned short* ws16 = (unsigned short*)d_ws;
  unsigned short* qb   = ws16;                       // 2M elems each
  unsigned short* kb   = qb + 2097152;
  unsigned short* vb   = kb + 2097152;
  unsigned short* vT   = vb + 2097152;
  unsigned short* buf5 = vT + 2097152;               // Qbf -> ctx
  unsigned short* buf6 = buf5 + 2097152;             // Kbf
  unsigned short* buf7 = buf6 + 2097152;             // Vbf
  float* l_row = (float*)(buf7 + 2097152);           // (16,2048) f32
  unsigned short* wqb = (unsigned short*)(l_row + 32768);   // 1M elems each
  unsigned short* wkb = wqb + 1048576;
  unsigned short* wvb = wkb + 1048576;
  unsigned short* wob = wvb + 1048576;

  unsigned short* Qbf = buf5;   // dead after qkv_gemm; reused as ctx
  unsigned short* Kbf = buf6;
  unsigned short* Vbf = buf7;
  unsigned short* ctx = buf5;

  dim3 blk(256);
  cvt7<<<dim3(1024, 7), blk, 0, stream>>>(
      Q, K, V, Wq, Wk, Wv, Wo, Qbf, Kbf, Vbf, wqb, wkb, wvb, wob);
  qkv_gemm<<<dim3(DDIM / 128, PP / 128, 3), blk, 0, stream>>>(
      Qbf, Kbf, Vbf, wqb, wkb, wvb, bq, bk, bv, qb, kb, vb);
  transpose_v<<<dim3(SSEQ / 64, DDIM / 64), blk, 0, stream>>>(vb, vT);
  scorespv<<<dim3(512), blk, 0, stream>>>(
      qb, kb, vT, prev, ch_gate, raw, l_row, ctx);
  attn_norm<<<dim3(2048), blk, 0, stream>>>(raw, l_row, attn);
  out_gemm<<<dim3(DDIM / 128, PP / 128), blk, 0, stream>>>(ctx, wob, bo, out);
}

// Round 21
// 262.894 us; speedup vs baseline: 1.1321x; 1.0584x over previous
//
#include <hip/hip_runtime.h>

#define PP 2048     // P (pred rows)
#define SSEQ 2048   // S (key rows)
#define DDIM 1024   // D
#define NH 16       // heads
#define DH 64       // head dim

typedef __attribute__((ext_vector_type(4))) float f32x4;
typedef __attribute__((ext_vector_type(8))) short bf16x8;
typedef __attribute__((ext_vector_type(4))) short bf16x4;

__device__ __forceinline__ short f2bf(float f) {
  unsigned u = __builtin_bit_cast(unsigned, f);
  u += 0x7FFFu + ((u >> 16) & 1u);   // RNE
  return (short)(u >> 16);
}
__device__ __forceinline__ float bf2f(unsigned short u) {
  return __builtin_bit_cast(float, ((unsigned)u) << 16);
}
__device__ __forceinline__ void gld_lds16(const void* g, void* l) {
  __builtin_amdgcn_global_load_lds(
      (const __attribute__((address_space(1))) void*)g,
      (__attribute__((address_space(3))) void*)l, 16, 0, 0);
}

// ---------------- bf16 conversion: 7 buffers in one launch ----------------
__global__ __launch_bounds__(256) void cvt7(
    const float* __restrict__ s0, const float* __restrict__ s1, const float* __restrict__ s2,
    const float* __restrict__ s3, const float* __restrict__ s4, const float* __restrict__ s5,
    const float* __restrict__ s6,
    unsigned short* __restrict__ d0, unsigned short* __restrict__ d1, unsigned short* __restrict__ d2,
    unsigned short* __restrict__ d3, unsigned short* __restrict__ d4, unsigned short* __restrict__ d5,
    unsigned short* __restrict__ d6) {
  const int z = blockIdx.y;
  const float* s = (z == 0) ? s0 : (z == 1) ? s1 : (z == 2) ? s2 : (z == 3) ? s3
                 : (z == 4) ? s4 : (z == 5) ? s5 : s6;
  unsigned short* d = (z == 0) ? d0 : (z == 1) ? d1 : (z == 2) ? d2 : (z == 3) ? d3
                    : (z == 4) ? d4 : (z == 5) ? d5 : d6;
  const size_t n = (z < 3) ? (size_t)PP * DDIM : (size_t)DDIM * DDIM;
  const size_t i = ((size_t)blockIdx.x * 256 + threadIdx.x) * 8;
  if (i >= n) return;
  const float4 x0 = *(const float4*)(s + i);
  const float4 x1 = *(const float4*)(s + i + 4);
  bf16x8 o;
  o[0] = f2bf(x0.x); o[1] = f2bf(x0.y); o[2] = f2bf(x0.z); o[3] = f2bf(x0.w);
  o[4] = f2bf(x1.x); o[5] = f2bf(x1.y); o[6] = f2bf(x1.z); o[7] = f2bf(x1.w);
  *(bf16x8*)(d + i) = o;
}

// ---------------- GEMM (m97 structure): Y[2048][1024] = A @ B^T + bias ------
template<int YF32>
__device__ __forceinline__ void gemm128_body(
    const int m0, const int n0,
    const unsigned short* __restrict__ A, const unsigned short* __restrict__ B,
    const float* __restrict__ bias, void* __restrict__ Yv) {
  __shared__ unsigned short As[4096];   // 128x32 linear
  __shared__ unsigned short Bs[4096];
  const int tid = threadIdx.x, lane = tid & 63, w = tid >> 6;
  const int g = lane >> 4, ln = lane & 15;
  const int wm = (w >> 1) * 64, wn = (w & 1) * 64;
  const int sr = tid >> 2, sc = (tid & 3) * 8;
  unsigned short* asd0 = As + w * 512;
  unsigned short* asd1 = As + 2048 + w * 512;
  unsigned short* bsd0 = Bs + w * 512;
  unsigned short* bsd1 = Bs + 2048 + w * 512;
  f32x4 acc[4][4] = {};
  for (int k0 = 0; k0 < DDIM; k0 += 32) {
    __syncthreads();
    gld_lds16(A + (size_t)(m0 + sr) * DDIM + k0 + sc, asd0);
    gld_lds16(A + (size_t)(m0 + 64 + sr) * DDIM + k0 + sc, asd1);
    gld_lds16(B + (size_t)(n0 + sr) * DDIM + k0 + sc, bsd0);
    gld_lds16(B + (size_t)(n0 + 64 + sr) * DDIM + k0 + sc, bsd1);
    __syncthreads();
    bf16x8 a[4], b[4];
#pragma unroll
    for (int mi = 0; mi < 4; ++mi) a[mi] = *(const bf16x8*)&As[(wm + mi * 16 + ln) * 32 + g * 8];
#pragma unroll
    for (int ni = 0; ni < 4; ++ni) b[ni] = *(const bf16x8*)&Bs[(wn + ni * 16 + ln) * 32 + g * 8];
#pragma unroll
    for (int mi = 0; mi < 4; ++mi)
#pragma unroll
      for (int ni = 0; ni < 4; ++ni)
        acc[mi][ni] = __builtin_amdgcn_mfma_f32_16x16x32_bf16(a[mi], b[ni], acc[mi][ni], 0, 0, 0);
  }
#pragma unroll
  for (int mi = 0; mi < 4; ++mi)
#pragma unroll
    for (int ni = 0; ni < 4; ++ni) {
      const int n = n0 + wn + ni * 16 + ln;
      const float bs = bias[n];
#pragma unroll
      for (int r = 0; r < 4; ++r) {
        const int m = m0 + wm + mi * 16 + g * 4 + r;
        const float v = acc[mi][ni][r] + bs;
        if (YF32) ((float*)Yv)[(size_t)m * DDIM + n] = v;
        else ((unsigned short*)Yv)[(size_t)m * DDIM + n] = (unsigned short)f2bf(v);
      }
    }
}

__global__ __launch_bounds__(256, 2) void qkv_gemm(
    const unsigned short* __restrict__ Qb, const unsigned short* __restrict__ Kb,
    const unsigned short* __restrict__ Vb,
    const unsigned short* __restrict__ Wq, const unsigned short* __restrict__ Wk,
    const unsigned short* __restrict__ Wv,
    const float* __restrict__ bq, const float* __restrict__ bk, const float* __restrict__ bv,
    unsigned short* __restrict__ qo, unsigned short* __restrict__ ko,
    unsigned short* __restrict__ vo) {
  const int z = blockIdx.z;
  gemm128_body<0>(blockIdx.y * 128, blockIdx.x * 128,
                  (z == 0) ? Qb : (z == 1) ? Kb : Vb,
                  (z == 0) ? Wq : (z == 1) ? Wk : Wv,
                  (z == 0) ? bq : (z == 1) ? bk : bv,
                  (z == 0) ? qo : (z == 1) ? ko : vo);
}

// ---------------- V transpose: vT[d][s] = vb[s][d] ----------------
__global__ __launch_bounds__(256) void transpose_v(
    const unsigned short* __restrict__ vb, unsigned short* __restrict__ vT) {
  __shared__ unsigned short t[64][72];
  const int tid = threadIdx.x;
  const int sb = blockIdx.x * 64, db = blockIdx.y * 64;
#pragma unroll
  for (int pass = 0; pass < 2; ++pass) {
    const int e = pass * 2048 + tid * 8;
    const int r = e >> 6, c = e & 63;
    *(bf16x8*)&t[r][c] = *(const bf16x8*)(vb + (size_t)(sb + r) * DDIM + db + c);
  }
  __syncthreads();
#pragma unroll
  for (int pass = 0; pass < 2; ++pass) {
    const int e = pass * 2048 + tid * 8;
    const int r = e >> 6, c = e & 63;   // r: d row, c: s col
    bf16x8 ov;
#pragma unroll
    for (int u = 0; u < 8; ++u) ov[u] = (short)t[c + u][r];
    *(bf16x8*)(vT + (size_t)(db + r) * SSEQ + sb + c) = ov;
  }
}

// ---------------- scorespv v7 (R20 champion, byte-identical) ----------------
__global__ __launch_bounds__(256, 2) void scorespv(
    const unsigned short* __restrict__ qb, const unsigned short* __restrict__ kb,
    const unsigned short* __restrict__ vT,
    const float* __restrict__ prev, const float* __restrict__ ch_gate,
    float* __restrict__ raw, float* __restrict__ l_row,
    unsigned short* __restrict__ ctx) {
  __shared__ float Rs[4][16][132];          // 33.8KB
  __shared__ float lS[4][16];
  __shared__ unsigned short Ks[2][8192];    // 2 x (128 rows x 64 cols) = 32KB
  const int tid = threadIdx.x, lane = tid & 63, w = tid >> 6;
  const int b = blockIdx.x;
  const int h = (b & 7) * 2 + ((b >> 3) & 1);            // XCD-local head pairs
  const int ptb = (b & 255) >> 4;
  const int pt = (b < 256) ? ptb : (31 - ptb);           // triangle pairing
  const int p0 = pt * 64, wr = w * 16;
  const int g = lane >> 4, ln = lane & 15;
  const int myp = p0 + wr + ln;
  const int pc = p0 >> 8;

  const int strow = w * 32 + (lane >> 3);
  const int scol = (((lane & 7) << 4) ^ ((lane >> 3) << 4)) >> 1;

  bf16x8 aq[2];
#pragma unroll
  for (int ks = 0; ks < 2; ++ks)
    aq[ks] = *(const bf16x8*)(qb + (size_t)myp * DDIM + h * DH + ks * 32 + g * 8);

  f32x4 U[4] = {};
  float lsum = 0.f;
  const size_t rowb = ((size_t)myp * NH + h) * SSEQ;

  // prologue: stage K tile 0 + prefetch prev tile 0
#pragma unroll
  for (int i = 0; i < 4; ++i)
    gld_lds16(kb + (size_t)(strow + i * 8) * DDIM + h * DH + scol,
              &Ks[0][(w * 32 + i * 8) * 64]);
  f32x4 pv[8];
#pragma unroll
  for (int ks = 0; ks < 4; ++ks) {
    pv[2 * ks]     = __builtin_nontemporal_load((const f32x4*)(prev + rowb + ks * 32 + g * 8));
    pv[2 * ks + 1] = __builtin_nontemporal_load((const f32x4*)(prev + rowb + ks * 32 + g * 8 + 4));
  }
  __syncthreads();   // K tile 0 staged

  for (int t = 0; t < 16; ++t) {
    const int s0 = t * 128;
    const float gate = (ch_gate[pc * 8 + (s0 >> 8)] >= 0.f) ? 1.f : 0.f;
    if (t < 15) {
#pragma unroll
      for (int i = 0; i < 4; ++i)
        gld_lds16(kb + (size_t)(s0 + 128 + strow + i * 8) * DDIM + h * DH + scol,
                  &Ks[(t + 1) & 1][(w * 32 + i * 8) * 64]);
    }
    const char* Kbuf = (const char*)Ks[t & 1];
#pragma unroll
    for (int half = 0; half < 2; ++half) {
      f32x4 acc[4] = {};
#pragma unroll
      for (int ks = 0; ks < 2; ++ks)
#pragma unroll
        for (int nj = 0; nj < 4; ++nj) {
          const int row = half * 64 + nj * 16 + ln;
          const bf16x8 bk = *(const bf16x8*)(Kbuf + row * 128 + ((ks * 64 + g * 16) ^ ((ln & 7) << 4)));
          acc[nj] = __builtin_amdgcn_mfma_f32_16x16x32_bf16(aq[ks], bk, acc[nj], 0, 0, 0);
        }
#pragma unroll
      for (int nj = 0; nj < 4; ++nj)
#pragma unroll
        for (int r = 0; r < 4; ++r)
          Rs[w][g * 4 + r][half * 64 + nj * 16 + ln] = acc[nj][r];
    }
    f32x4 pvn[8];
    if (t < 15) {
#pragma unroll
      for (int ks = 0; ks < 4; ++ks) {
        pvn[2 * ks]     = __builtin_nontemporal_load((const f32x4*)(prev + rowb + s0 + 128 + ks * 32 + g * 8));
        pvn[2 * ks + 1] = __builtin_nontemporal_load((const f32x4*)(prev + rowb + s0 + 128 + ks * 32 + g * 8 + 4));
      }
    }
    f32x4 v[8];
#pragma unroll
    for (int ks = 0; ks < 4; ++ks)
#pragma unroll
      for (int hf = 0; hf < 2; ++hf) {
        const int c0 = ks * 32 + g * 8 + hf * 4;
        const f32x4 sc = *(const f32x4*)&Rs[w][ln][c0];
        f32x4 vv;
        vv[0] = fmaf(sc[0], 0.125f, pv[ks * 2 + hf][0]) * gate;
        vv[1] = fmaf(sc[1], 0.125f, pv[ks * 2 + hf][1]) * gate;
        vv[2] = fmaf(sc[2], 0.125f, pv[ks * 2 + hf][2]) * gate;
        vv[3] = fmaf(sc[3], 0.125f, pv[ks * 2 + hf][3]) * gate;
        v[ks * 2 + hf] = vv;
        *(f32x4*)(raw + rowb + s0 + c0) = vv;   // normal store -> L3 for attn_norm
      }
    if (s0 <= p0 + wr + 15) {
      bf16x8 pa[4];
#pragma unroll
      for (int ks = 0; ks < 4; ++ks) {
        const int cb = s0 + ks * 32 + g * 8;
        float e[8];
#pragma unroll
        for (int j = 0; j < 4; ++j) {
          e[j]     = (cb + j     <= myp) ? __expf(v[2 * ks][j])     : 0.f;
          e[j + 4] = (cb + j + 4 <= myp) ? __expf(v[2 * ks + 1][j]) : 0.f;
        }
        lsum += ((e[0] + e[1]) + (e[2] + e[3])) + ((e[4] + e[5]) + (e[6] + e[7]));
        bf16x8 pk;
#pragma unroll
        for (int j = 0; j < 8; ++j) pk[j] = f2bf(e[j]);
        pa[ks] = pk;
      }
#pragma unroll
      for (int nj = 0; nj < 4; ++nj) {
        const size_t vb0 = (size_t)(h * DH + nj * 16 + ln) * SSEQ + s0;
        const bf16x8 b0 = *(const bf16x8*)(vT + vb0 + g * 8);
        const bf16x8 b1 = *(const bf16x8*)(vT + vb0 + 32 + g * 8);
        const bf16x8 b2 = *(const bf16x8*)(vT + vb0 + 64 + g * 8);
        const bf16x8 b3 = *(const bf16x8*)(vT + vb0 + 96 + g * 8);
        U[nj] = __builtin_amdgcn_mfma_f32_16x16x32_bf16(pa[0], b0, U[nj], 0, 0, 0);
        U[nj] = __builtin_amdgcn_mfma_f32_16x16x32_bf16(pa[1], b1, U[nj], 0, 0, 0);
        U[nj] = __builtin_amdgcn_mfma_f32_16x16x32_bf16(pa[2], b2, U[nj], 0, 0, 0);
        U[nj] = __builtin_amdgcn_mfma_f32_16x16x32_bf16(pa[3], b3, U[nj], 0, 0, 0);
      }
    }
    if (t < 15) {
#pragma unroll
      for (int i = 0; i < 8; ++i) pv[i] = pvn[i];
    }
    __syncthreads();   // next K tile staged; all waves done with Ks[t&1]
  }
  lsum += __shfl_xor(lsum, 16);
  lsum += __shfl_xor(lsum, 32);
  if (g == 0) {
    lS[w][ln] = lsum;
    l_row[h * PP + myp] = lsum;
  }
  float il4[4];
#pragma unroll
  for (int r = 0; r < 4; ++r) il4[r] = 1.f / lS[w][g * 4 + r];
#pragma unroll
  for (int nj = 0; nj < 4; ++nj)
#pragma unroll
    for (int r = 0; r < 4; ++r) {
      const int p = p0 + wr + g * 4 + r;
      ctx[(size_t)p * DDIM + h * DH + nj * 16 + ln] = (unsigned short)f2bf(U[nj][r] * il4[r]);
    }
}

// ---------------- norm_out: co-launched attn_norm + out_gemm ----------------
// blocks 0..127: out projection (128x128 tiles; only half the GPU) -- issued
// first so they spread across XCDs; blocks 128..2175: attn_norm streaming.
// The out-projection runs in the shadow of attn_norm's 45us streaming phase.
__global__ __launch_bounds__(256, 2) void norm_out(
    const float* __restrict__ raw, const float* __restrict__ l_row,
    float* __restrict__ attn,
    const unsigned short* __restrict__ ctx, const unsigned short* __restrict__ wob,
    const float* __restrict__ bo, float* __restrict__ out) {
  const int b = blockIdx.x;
  if (b < 128) {
    gemm128_body<1>((b >> 3) * 128, (b & 7) * 128, ctx, wob, bo, out);
    return;
  }
  const int bb = b - 128;
  const int lo = bb & 255, k8 = bb >> 8;
  const int h = lo & 15, ptb = lo >> 4;
  const int pt = ptb + 16 * k8;                 // 0..127
  const int p0 = pt * 16;
  __shared__ float ilS[16];
  if (threadIdx.x < 16) ilS[threadIdx.x] = 1.f / l_row[h * PP + p0 + threadIdx.x];
  __syncthreads();
  const int limit = ((p0 + 16 + 127) >> 7) << 7;
  const int col = threadIdx.x * 4;
  for (int c0 = 0; c0 < SSEQ; c0 += 1024) {
    const int c = c0 + col;
#pragma unroll 4
    for (int r = 0; r < 16; ++r) {
      const int p = p0 + r;
      const size_t base = ((size_t)p * NH + h) * SSEQ + c;
      f32x4 av = {0.f, 0.f, 0.f, 0.f};
      if (c < limit) {
        const float il = ilS[r];
        const f32x4 rv = *(const f32x4*)(raw + base);
        av[0] = (c + 0 <= p) ? __expf(rv[0]) * il : 0.f;
        av[1] = (c + 1 <= p) ? __expf(rv[1]) * il : 0.f;
        av[2] = (c + 2 <= p) ? __expf(rv[2]) * il : 0.f;
        av[3] = (c + 3 <= p) ? __expf(rv[3]) * il : 0.f;
      }
      __builtin_nontemporal_store(av, (f32x4*)(attn + base));
    }
  }
}

extern "C" void kernel_launch(void* const* d_in, const int* in_sizes, int n_in,
                              void* d_out, int out_size, void* d_ws, size_t ws_size,
                              hipStream_t stream) {
  (void)in_sizes; (void)n_in; (void)out_size; (void)ws_size;
  const float* Q    = (const float*)d_in[0];
  const float* K    = (const float*)d_in[1];
  const float* V    = (const float*)d_in[2];
  const float* prev = (const float*)d_in[3];
  const float* Wq   = (const float*)d_in[4];
  const float* bq   = (const float*)d_in[5];
  const float* Wk   = (const float*)d_in[6];
  const float* bk   = (const float*)d_in[7];
  const float* Wv   = (const float*)d_in[8];
  const float* bv   = (const float*)d_in[9];
  const float* Wo   = (const float*)d_in[10];
  const float* bo   = (const float*)d_in[11];
  const float* ch_gate = (const float*)d_in[12];

  float* out  = (float*)d_out;                       // (2048,1024)
  float* attn = out + (size_t)PP * DDIM;             // (2048,16,2048)
  float* raw  = attn + (size_t)PP * NH * SSEQ;       // (2048,16,2048)

  // ws layout (~36MB, lifetime-overlapped):
  unsigned short* ws16 = (unsigned short*)d_ws;
  unsigned short* qb   = ws16;                       // 2M elems each
  unsigned short* kb   = qb + 2097152;
  unsigned short* vb   = kb + 2097152;
  unsigned short* vT   = vb + 2097152;
  unsigned short* buf5 = vT + 2097152;               // Qbf -> ctx
  unsigned short* buf6 = buf5 + 2097152;             // Kbf
  unsigned short* buf7 = buf6 + 2097152;             // Vbf
  float* l_row = (float*)(buf7 + 2097152);           // (16,2048) f32
  unsigned short* wqb = (unsigned short*)(l_row + 32768);   // 1M elems each
  unsigned short* wkb = wqb + 1048576;
  unsigned short* wvb = wkb + 1048576;
  unsigned short* wob = wvb + 1048576;

  unsigned short* Qbf = buf5;   // dead after qkv_gemm; reused as ctx
  unsigned short* Kbf = buf6;
  unsigned short* Vbf = buf7;
  unsigned short* ctx = buf5;

  dim3 blk(256);
  cvt7<<<dim3(1024, 7), blk, 0, stream>>>(
      Q, K, V, Wq, Wk, Wv, Wo, Qbf, Kbf, Vbf, wqb, wkb, wvb, wob);
  qkv_gemm<<<dim3(DDIM / 128, PP / 128, 3), blk, 0, stream>>>(
      Qbf, Kbf, Vbf, wqb, wkb, wvb, bq, bk, bv, qb, kb, vb);
  transpose_v<<<dim3(SSEQ / 64, DDIM / 64), blk, 0, stream>>>(vb, vT);
  scorespv<<<dim3(512), blk, 0, stream>>>(
      qb, kb, vT, prev, ch_gate, raw, l_row, ctx);
  norm_out<<<dim3(2176), blk, 0, stream>>>(
      raw, l_row, attn, ctx, wob, bo, out);
}